// Round 1
// baseline (1219.145 us; speedup 1.0000x reference)
//
#include <hip/hip_runtime.h>
#include <stdint.h>

// ---------------------------------------------------------------------------
// EW_MHSA_Hybrid: x(32,256,56,56) --1x1conv--> qk(512ch), v(256ch,ReLU)
// then 7x7 window attention over remote (dilated) + close (contiguous)
// partitions, summed. Output fp32 (32,256,56,56).
//
// ws layout (needs ~206 MB):
//   [0, 393216)                 Wb   : bf16 weights [768][256] (qk rows 0..511, v rows 512..767)
//   [393216, 51773440)          xT   : bf16 x, pixel-major [b*3136+p][256ch], 16B groups XOR-swizzled by (p&7)
//   [51773440, 205914112)       qkv  : bf16 [b*3136+p][768]  (q:0..255, k:256..511, v:512..767; v has ReLU)
// ---------------------------------------------------------------------------

typedef float f32x4 __attribute__((ext_vector_type(4)));
typedef __attribute__((ext_vector_type(8))) short short8;

union V16 { uint4 u; short8 s; unsigned short h[8]; };

typedef const __attribute__((address_space(1))) uint32_t* gp_t;
typedef __attribute__((address_space(3))) uint32_t* lp_t;

__device__ __forceinline__ void async16(const void* g, void* l) {
  // 16B per lane, LDS dst = uniform base + lane*16
  __builtin_amdgcn_global_load_lds((gp_t)g, (lp_t)l, 16, 0, 0);
}

__device__ __forceinline__ unsigned short f2bf(float f) {
  union { float f; uint32_t u; } a; a.f = f;
  uint32_t u = a.u;
  return (unsigned short)((u + 0x7FFFu + ((u >> 16) & 1u)) >> 16); // RNE
}

// ------------------------- kernel 0: weight convert -------------------------
__global__ __launch_bounds__(256) void k_wconv(const float* __restrict__ qk_w,
                                               const float* __restrict__ v_w,
                                               unsigned short* __restrict__ Wb) {
  int i = blockIdx.x * 256 + threadIdx.x;   // 768*256 = 196608 total
  int o = i >> 8, c = i & 255;
  float v = (o < 512) ? qk_w[o * 256 + c] : v_w[(o - 512) * 256 + c];
  Wb[i] = f2bf(v);
}

// --------------------- kernel 1: x -> bf16 NHWC (swizzled) ------------------
// grid (49, 8, 32), block 256. Each thread: 1 pixel x 8 channels -> one 16B group.
__global__ __launch_bounds__(256) void k_xpose(const float* __restrict__ x,
                                               unsigned short* __restrict__ xT) {
  const int t = threadIdx.x;
  const int p = blockIdx.x * 64 + (t >> 2);     // pixel within batch
  const int sub = t & 3;
  const int c0 = blockIdx.y * 32 + sub * 8;     // channel group start
  const int b = blockIdx.z;
  const float* xp = x + ((size_t)(b * 256 + c0)) * 3136 + p;
  unsigned short vv[8];
#pragma unroll
  for (int j = 0; j < 8; j++) vv[j] = f2bf(xp[(size_t)j * 3136]);
  uint4 u;
  u.x = (uint32_t)vv[0] | ((uint32_t)vv[1] << 16);
  u.y = (uint32_t)vv[2] | ((uint32_t)vv[3] << 16);
  u.z = (uint32_t)vv[4] | ((uint32_t)vv[5] << 16);
  u.w = (uint32_t)vv[6] | ((uint32_t)vv[7] << 16);
  const int g = (c0 >> 3) & 7;      // group index within 128B block
  const int kb = c0 >> 6;           // which 128B block (K-tile of 64ch)
  char* dst = (char*)xT + ((size_t)(b * 3136 + p)) * 512 + kb * 128 + ((g ^ (p & 7)) << 4);
  *(uint4*)dst = u;
}

// ------------------------- kernel 2: conv GEMM (MFMA) -----------------------
// C[o][px] = sum_c W[o][c] * x[px][c].  M=o (A=W from global), N=px (B from LDS).
// grid (25, 6, 32): 128-pixel x 128-outch tiles, K=256 in 4 steps of 64.
__global__ __launch_bounds__(256) void k_conv(const unsigned short* __restrict__ Wb,
                                              const unsigned short* __restrict__ xT,
                                              unsigned short* __restrict__ qkv) {
  __shared__ uint4 lds4[1024];     // 16 KB: 128 px rows x 128 B (swizzled groups)
  char* lds = (char*)lds4;
  const int tid = threadIdx.x;
  const int lane = tid & 63, wave = tid >> 6;
  const int lid = lane & 15, quad = lane >> 4;
  const int p0 = blockIdx.x * 128;
  const int o0 = blockIdx.y * 128;
  const int b = blockIdx.z;
  const bool isv = (blockIdx.y >= 4);                 // v rows get ReLU
  const int m_off = (wave & 1) * 64, n_off = (wave >> 1) * 64;
  const int psub = lane >> 3, chunk = lane & 7;
  const size_t rowb = (size_t)(b * 3136 + p0);
  const char* xTb = (const char*)xT;

  f32x4 acc[4][4];
#pragma unroll
  for (int mi = 0; mi < 4; mi++)
#pragma unroll
    for (int ni = 0; ni < 4; ni++) { f32x4 z = {0.f, 0.f, 0.f, 0.f}; acc[mi][ni] = z; }

  for (int kk = 0; kk < 256; kk += 64) {
#pragma unroll
    for (int r = 0; r < 4; r++) {
      int i = wave * 4 + r;                           // 16 instrs cover 128 rows
      const char* g = xTb + (rowb + i * 8 + psub) * 512 + kk * 2 + chunk * 16;
      async16(g, lds + i * 1024);
    }
    __syncthreads();

    V16 a[4][2], bf[4][2];
#pragma unroll
    for (int mi = 0; mi < 4; mi++) {
      int o = o0 + m_off + mi * 16 + lid;
#pragma unroll
      for (int ks = 0; ks < 2; ks++)
        a[mi][ks].u = *(const uint4*)(Wb + o * 256 + kk + ks * 32 + quad * 8);
    }
#pragma unroll
    for (int ni = 0; ni < 4; ni++) {
      int px = n_off + ni * 16 + lid;                 // LDS row 0..127
#pragma unroll
      for (int ks = 0; ks < 2; ks++) {
        int gl = ks * 4 + quad;
        bf[ni][ks].u = *(const uint4*)(lds + px * 128 + ((gl ^ (px & 7)) << 4));
      }
    }
#pragma unroll
    for (int mi = 0; mi < 4; mi++)
#pragma unroll
      for (int ni = 0; ni < 4; ni++) {
        acc[mi][ni] = __builtin_amdgcn_mfma_f32_16x16x32_bf16(a[mi][0].s, bf[ni][0].s, acc[mi][ni], 0, 0, 0);
        acc[mi][ni] = __builtin_amdgcn_mfma_f32_16x16x32_bf16(a[mi][1].s, bf[ni][1].s, acc[mi][ni], 0, 0, 0);
      }
    __syncthreads();
  }

  // epilogue: lane holds 4 consecutive o at one pixel -> 8B packed store
#pragma unroll
  for (int mi = 0; mi < 4; mi++) {
    int o = o0 + m_off + mi * 16 + quad * 4;
#pragma unroll
    for (int ni = 0; ni < 4; ni++) {
      int px = p0 + n_off + ni * 16 + lid;
      if (px < 3136) {
        f32x4 v = acc[mi][ni];
        if (isv) {
          v.x = fmaxf(v.x, 0.f); v.y = fmaxf(v.y, 0.f);
          v.z = fmaxf(v.z, 0.f); v.w = fmaxf(v.w, 0.f);
        }
        ushort4 u;
        u.x = f2bf(v.x); u.y = f2bf(v.y); u.z = f2bf(v.z); u.w = f2bf(v.w);
        *(ushort4*)(qkv + ((size_t)(b * 3136 + px)) * 768 + o) = u;
      }
    }
  }
}

// --------------------------- kernel 3/4: attention --------------------------
// One block per (window, batch); wave = head. 49 pixels padded to 64.
// QK^T and PV via 16x16x32 bf16 MFMA; Q/K/V frags direct from global;
// normalized P (bf16) round-trips through XOR-swizzled LDS (8 KB/wave).
template <int CLOSE>
__global__ __launch_bounds__(256) void k_attn(const unsigned short* __restrict__ qkv,
                                              float* __restrict__ out) {
  __shared__ uint4 smem4[2048];   // 32 KB = 4 waves x 8 KB P-buffer
  const int lane = threadIdx.x & 63;
  const int head = threadIdx.x >> 6;
  const int lid = lane & 15, quad = lane >> 4;
  char* Pb = (char*)smem4 + head * 8192;
  const int w = blockIdx.x, b = blockIdx.y;
  const int i1 = w >> 3, i2 = w & 7;
  const size_t base = (size_t)b * 3136;

  auto pix = [&](int t) -> int {  // window slot t (0..48) -> pixel index
    int h1 = t / 7, w1 = t - h1 * 7;
    int h, ww;
    if (CLOSE) { h = i1 * 7 + h1; ww = i2 * 7 + w1; }
    else       { h = h1 * 8 + i1; ww = w1 * 8 + i2; }
    return h * 56 + ww;
  };

  // --- hoisted V B-frags: B[k=key][n=dh], lane n=lid(+16ni), keys quad*8+j ---
  V16 vf[2][4];
#pragma unroll
  for (int ks = 0; ks < 2; ks++)
#pragma unroll
    for (int j = 0; j < 8; j++) {
      int key = ks * 32 + quad * 8 + j;
      int p = pix(min(key, 48));                       // clamp: P cols >=49 are 0
      const unsigned short* vp = qkv + (base + p) * 768 + 512 + head * 64;
#pragma unroll
      for (int ni = 0; ni < 4; ni++) vf[ks][ni].h[j] = vp[ni * 16 + lid];
    }

  // --- Q A-frags and K^T B-frags (16B per lane; 4 quads = full 64B line) ---
  V16 qf[4][2], kf[4][2];
#pragma unroll
  for (int mi = 0; mi < 4; mi++) {
    int p = pix(min(mi * 16 + lid, 48));
    const unsigned short* qp = qkv + (base + p) * 768 + head * 64;
#pragma unroll
    for (int ks = 0; ks < 2; ks++) qf[mi][ks].u = *(const uint4*)(qp + ks * 32 + quad * 8);
  }
#pragma unroll
  for (int ni = 0; ni < 4; ni++) {
    int p = pix(min(ni * 16 + lid, 48));
    const unsigned short* kp = qkv + (base + p) * 768 + 256 + head * 64;
#pragma unroll
    for (int ks = 0; ks < 2; ks++) kf[ni][ks].u = *(const uint4*)(kp + ks * 32 + quad * 8);
  }

  // --- logits S = Q K^T ---
  f32x4 s[4][4];
#pragma unroll
  for (int mi = 0; mi < 4; mi++)
#pragma unroll
    for (int ni = 0; ni < 4; ni++) {
      f32x4 z = {0.f, 0.f, 0.f, 0.f};
      z = __builtin_amdgcn_mfma_f32_16x16x32_bf16(qf[mi][0].s, kf[ni][0].s, z, 0, 0, 0);
      z = __builtin_amdgcn_mfma_f32_16x16x32_bf16(qf[mi][1].s, kf[ni][1].s, z, 0, 0, 0);
      s[mi][ni] = z;
    }

  // --- softmax rows (row = mi*16+quad*4+r), cols masked at >=49 ---
  bool valid[4];
#pragma unroll
  for (int ni = 0; ni < 4; ni++) valid[ni] = (ni * 16 + lid) < 49;
  const float SC = 0.18033688011112042f;  // (1/8) * log2(e)
#pragma unroll
  for (int mi = 0; mi < 4; mi++) {
#pragma unroll
    for (int r = 0; r < 4; r++) {
      float m = -3.0e38f;
#pragma unroll
      for (int ni = 0; ni < 4; ni++) m = valid[ni] ? fmaxf(m, s[mi][ni][r]) : m;
#pragma unroll
      for (int d = 1; d < 16; d <<= 1) m = fmaxf(m, __shfl_xor(m, d, 64));
      float e[4]; float sum = 0.f;
#pragma unroll
      for (int ni = 0; ni < 4; ni++) {
        float t = valid[ni] ? exp2f((s[mi][ni][r] - m) * SC) : 0.f;
        e[ni] = t; sum += t;
      }
#pragma unroll
      for (int d = 1; d < 16; d <<= 1) sum += __shfl_xor(sum, d, 64);
      float inv = __builtin_amdgcn_rcpf(sum);          // fold 1/rowsum into P
      int row = mi * 16 + quad * 4 + r;
#pragma unroll
      for (int ni = 0; ni < 4; ni++) {
        int col = ni * 16 + lid;
        *(unsigned short*)(Pb + row * 128 + (((col >> 3) ^ (row & 7)) << 4) + (col & 7) * 2) =
            f2bf(e[ni] * inv);
      }
    }
  }
  __syncthreads();  // DS write->read ordering (each wave reads only its own P)

  // --- O = P V ---
  V16 pf[4][2];
#pragma unroll
  for (int mi = 0; mi < 4; mi++) {
    int row = mi * 16 + lid;
#pragma unroll
    for (int ks = 0; ks < 2; ks++) {
      int gl = ks * 4 + quad;
      pf[mi][ks].u = *(const uint4*)(Pb + row * 128 + ((gl ^ (row & 7)) << 4));
    }
  }
  f32x4 o[4][4];
#pragma unroll
  for (int mi = 0; mi < 4; mi++)
#pragma unroll
    for (int ni = 0; ni < 4; ni++) {
      f32x4 z = {0.f, 0.f, 0.f, 0.f};
      z = __builtin_amdgcn_mfma_f32_16x16x32_bf16(pf[mi][0].s, vf[0][ni].s, z, 0, 0, 0);
      z = __builtin_amdgcn_mfma_f32_16x16x32_bf16(pf[mi][1].s, vf[1][ni].s, z, 0, 0, 0);
      o[mi][ni] = z;
    }

  // --- scatter to out (fp32 NCHW); remote writes, close accumulates ---
#pragma unroll
  for (int mi = 0; mi < 4; mi++) {
#pragma unroll
    for (int r = 0; r < 4; r++) {
      int q = mi * 16 + quad * 4 + r;
      if (q < 49) {
        int p = pix(q);
#pragma unroll
        for (int ni = 0; ni < 4; ni++) {
          int c = head * 64 + ni * 16 + lid;
          size_t idx = ((size_t)(b * 256 + c)) * 3136 + p;
          float val = o[mi][ni][r];
          if (CLOSE) out[idx] += val; else out[idx] = val;
        }
      }
    }
  }
}

// ------------------------------- launcher -----------------------------------
extern "C" void kernel_launch(void* const* d_in, const int* in_sizes, int n_in,
                              void* d_out, int out_size, void* d_ws, size_t ws_size,
                              hipStream_t stream) {
  (void)in_sizes; (void)n_in; (void)out_size; (void)ws_size;
  const float* x    = (const float*)d_in[0];
  const float* qk_w = (const float*)d_in[1];
  const float* v_w  = (const float*)d_in[2];
  float* out = (float*)d_out;
  char* ws = (char*)d_ws;
  unsigned short* Wb  = (unsigned short*)ws;                    // 393,216 B
  unsigned short* xT  = (unsigned short*)(ws + 393216);         // 51,380,224 B
  unsigned short* qkv = (unsigned short*)(ws + 51773440ull);    // 154,140,672 B

  hipLaunchKernelGGL(k_wconv, dim3(768), dim3(256), 0, stream, qk_w, v_w, Wb);
  hipLaunchKernelGGL(k_xpose, dim3(49, 8, 32), dim3(256), 0, stream, x, xT);
  hipLaunchKernelGGL(k_conv, dim3(25, 6, 32), dim3(256), 0, stream, Wb, xT, qkv);
  hipLaunchKernelGGL((k_attn<0>), dim3(64, 32), dim3(256), 0, stream, qkv, out); // remote: write
  hipLaunchKernelGGL((k_attn<1>), dim3(64, 32), dim3(256), 0, stream, qkv, out); // close: +=
}

// Round 2
// 413.937 us; speedup vs baseline: 2.9452x; 2.9452x over previous
//
#include <hip/hip_runtime.h>
#include <stdint.h>

// ---------------------------------------------------------------------------
// EW_MHSA_Hybrid: x(32,256,56,56) --1x1conv--> qk(512ch), v(256ch,ReLU)
// then 7x7 window attention over remote (dilated) + close (contiguous)
// partitions, summed. Output fp32 (32,256,56,56).
//
// ws layout (needs ~258 MB):
//   [0, 393216)             Wb  : bf16 weights [768][256]
//   [393216, 51773440)      xT  : bf16 x pixel-major [b*3136+p][256], swizzled
//                                 (DEAD after k_conv -> reused as oR)
//   [51773440, 205914112)   qkv : bf16 [b*3136+p][768] (q|k|v, v has ReLU)
//   [205914112, 257294336)  oC  : bf16 close-attn out, pixel-major [b*3136+p][256]
// ---------------------------------------------------------------------------

typedef float f32x4 __attribute__((ext_vector_type(4)));
typedef __attribute__((ext_vector_type(8))) short short8;

union V16 { uint4 u; short8 s; unsigned short h[8]; };

typedef const __attribute__((address_space(1))) uint32_t* gp_t;
typedef __attribute__((address_space(3))) uint32_t* lp_t;

__device__ __forceinline__ void async16(const void* g, void* l) {
  __builtin_amdgcn_global_load_lds((gp_t)g, (lp_t)l, 16, 0, 0);
}

__device__ __forceinline__ unsigned short f2bf(float f) {
  union { float f; uint32_t u; } a; a.f = f;
  uint32_t u = a.u;
  return (unsigned short)((u + 0x7FFFu + ((u >> 16) & 1u)) >> 16); // RNE
}

__device__ __forceinline__ float bf2f(uint32_t bits_hi16) {
  union { uint32_t u; float f; } a; a.u = bits_hi16; return a.f;
}

// ------------------------- kernel 0: weight convert -------------------------
__global__ __launch_bounds__(256) void k_wconv(const float* __restrict__ qk_w,
                                               const float* __restrict__ v_w,
                                               unsigned short* __restrict__ Wb) {
  int i = blockIdx.x * 256 + threadIdx.x;   // 768*256 = 196608
  int o = i >> 8, c = i & 255;
  float v = (o < 512) ? qk_w[o * 256 + c] : v_w[(o - 512) * 256 + c];
  Wb[i] = f2bf(v);
}

// --------------------- kernel 1: x -> bf16 NHWC (swizzled) ------------------
__global__ __launch_bounds__(256) void k_xpose(const float* __restrict__ x,
                                               unsigned short* __restrict__ xT) {
  const int t = threadIdx.x;
  const int p = blockIdx.x * 64 + (t >> 2);
  const int sub = t & 3;
  const int c0 = blockIdx.y * 32 + sub * 8;
  const int b = blockIdx.z;
  const float* xp = x + ((size_t)(b * 256 + c0)) * 3136 + p;
  unsigned short vv[8];
#pragma unroll
  for (int j = 0; j < 8; j++) vv[j] = f2bf(xp[(size_t)j * 3136]);
  uint4 u;
  u.x = (uint32_t)vv[0] | ((uint32_t)vv[1] << 16);
  u.y = (uint32_t)vv[2] | ((uint32_t)vv[3] << 16);
  u.z = (uint32_t)vv[4] | ((uint32_t)vv[5] << 16);
  u.w = (uint32_t)vv[6] | ((uint32_t)vv[7] << 16);
  const int g = (c0 >> 3) & 7;
  const int kb = c0 >> 6;
  char* dst = (char*)xT + ((size_t)(b * 3136 + p)) * 512 + kb * 128 + ((g ^ (p & 7)) << 4);
  *(uint4*)dst = u;
}

// ------------------------- kernel 2: conv GEMM (MFMA) -----------------------
// grid flat 4800 with XCD-batch affinity: batch b runs on XCD b%8.
__global__ __launch_bounds__(256) void k_conv(const unsigned short* __restrict__ Wb,
                                              const unsigned short* __restrict__ xT,
                                              unsigned short* __restrict__ qkv) {
  __shared__ uint4 lds4[1024];     // 16 KB: 128 px rows x 128 B (swizzled)
  char* lds = (char*)lds4;
  const int bi = blockIdx.x;                 // 0..4799
  const int xcd = bi & 7, g = bi >> 3;       // g: 0..599
  const int bgrp = g / 150;
  const int rem = g - bgrp * 150;
  const int b = xcd + 8 * bgrp;
  const int ot = rem / 25;
  const int pt = rem - ot * 25;
  const int p0 = pt * 128, o0 = ot * 128;
  const bool isv = (ot >= 4);

  const int tid = threadIdx.x;
  const int lane = tid & 63, wave = tid >> 6;
  const int lid = lane & 15, quad = lane >> 4;
  const int m_off = (wave & 1) * 64, n_off = (wave >> 1) * 64;
  const int psub = lane >> 3, chunk = lane & 7;
  const size_t rowb = (size_t)(b * 3136 + p0);
  const char* xTb = (const char*)xT;

  f32x4 acc[4][4];
#pragma unroll
  for (int mi = 0; mi < 4; mi++)
#pragma unroll
    for (int ni = 0; ni < 4; ni++) { f32x4 z = {0.f, 0.f, 0.f, 0.f}; acc[mi][ni] = z; }

  for (int kk = 0; kk < 256; kk += 64) {
#pragma unroll
    for (int r = 0; r < 4; r++) {
      int i = wave * 4 + r;
      const char* gp = xTb + (rowb + i * 8 + psub) * 512 + kk * 2 + chunk * 16;
      async16(gp, lds + i * 1024);
    }
    __syncthreads();

    V16 a[4][2], bf[4][2];
#pragma unroll
    for (int mi = 0; mi < 4; mi++) {
      int o = o0 + m_off + mi * 16 + lid;
#pragma unroll
      for (int ks = 0; ks < 2; ks++)
        a[mi][ks].u = *(const uint4*)(Wb + o * 256 + kk + ks * 32 + quad * 8);
    }
#pragma unroll
    for (int ni = 0; ni < 4; ni++) {
      int px = n_off + ni * 16 + lid;
#pragma unroll
      for (int ks = 0; ks < 2; ks++) {
        int gl = ks * 4 + quad;
        bf[ni][ks].u = *(const uint4*)(lds + px * 128 + ((gl ^ (px & 7)) << 4));
      }
    }
#pragma unroll
    for (int mi = 0; mi < 4; mi++)
#pragma unroll
      for (int ni = 0; ni < 4; ni++) {
        acc[mi][ni] = __builtin_amdgcn_mfma_f32_16x16x32_bf16(a[mi][0].s, bf[ni][0].s, acc[mi][ni], 0, 0, 0);
        acc[mi][ni] = __builtin_amdgcn_mfma_f32_16x16x32_bf16(a[mi][1].s, bf[ni][1].s, acc[mi][ni], 0, 0, 0);
      }
    __syncthreads();
  }

#pragma unroll
  for (int mi = 0; mi < 4; mi++) {
    int o = o0 + m_off + mi * 16 + quad * 4;
#pragma unroll
    for (int ni = 0; ni < 4; ni++) {
      int px = p0 + n_off + ni * 16 + lid;
      if (px < 3136) {
        f32x4 v = acc[mi][ni];
        if (isv) {
          v.x = fmaxf(v.x, 0.f); v.y = fmaxf(v.y, 0.f);
          v.z = fmaxf(v.z, 0.f); v.w = fmaxf(v.w, 0.f);
        }
        ushort4 u;
        u.x = f2bf(v.x); u.y = f2bf(v.y); u.z = f2bf(v.z); u.w = f2bf(v.w);
        *(ushort4*)(qkv + ((size_t)(b * 3136 + px)) * 768 + o) = u;
      }
    }
  }
}

// --------------------------- kernel 3: attention ----------------------------
// Both partitions in one dispatch, XCD-batch affinity. One block per
// (partition, window, batch); wave = head. 49 px padded to 64.
// Output: pixel-major bf16 scratch (oR remote / oC close).
__global__ __launch_bounds__(256) void k_attn(const unsigned short* __restrict__ qkv,
                                              unsigned short* __restrict__ oR,
                                              unsigned short* __restrict__ oC) {
  __shared__ uint4 smem4[2048];   // 32 KB = 4 waves x 8 KB P-buffer
  const int bi = blockIdx.x;                  // 0..4095
  const int xcd = bi & 7, g = bi >> 3;        // g: 0..511
  const int b = ((g >> 7) << 3) + xcd;        // batch: b%8 == xcd
  const int rem = g & 127;
  const int part = rem >> 6;                  // 0=remote, 1=close
  const int w = rem & 63;
  const int i1 = w >> 3, i2 = w & 7;
  const int off = part ? (i1 * 392 + i2 * 7) : (i1 * 56 + i2);
  const int sh  = part ? 56 : 448;
  const int sw  = part ? 1 : 8;
  unsigned short* __restrict__ oS = part ? oC : oR;

  const int lane = threadIdx.x & 63;
  const int head = threadIdx.x >> 6;
  const int lid = lane & 15, quad = lane >> 4;
  char* Pb = (char*)smem4 + head * 8192;
  const size_t base = (size_t)b * 3136;

  auto pix = [&](int t) -> int {  // window slot t (0..48) -> pixel index
    int h1 = (t * 37) >> 8;       // t/7 for t<=48
    int w1 = t - h1 * 7;
    return off + h1 * sh + w1 * sw;
  };

  // --- V B-frags: B[k=key][n=dh] ---
  V16 vf[2][4];
#pragma unroll
  for (int ks = 0; ks < 2; ks++)
#pragma unroll
    for (int j = 0; j < 8; j++) {
      int key = ks * 32 + quad * 8 + j;
      int p = pix(min(key, 48));                       // P cols >=49 are 0
      const unsigned short* vp = qkv + (base + p) * 768 + 512 + head * 64;
#pragma unroll
      for (int ni = 0; ni < 4; ni++) vf[ks][ni].h[j] = vp[ni * 16 + lid];
    }

  // --- Q A-frags / K^T B-frags (16B per lane) ---
  V16 qf[4][2], kf[4][2];
#pragma unroll
  for (int mi = 0; mi < 4; mi++) {
    int p = pix(min(mi * 16 + lid, 48));
    const unsigned short* qp = qkv + (base + p) * 768 + head * 64;
#pragma unroll
    for (int ks = 0; ks < 2; ks++) qf[mi][ks].u = *(const uint4*)(qp + ks * 32 + quad * 8);
  }
#pragma unroll
  for (int ni = 0; ni < 4; ni++) {
    int p = pix(min(ni * 16 + lid, 48));
    const unsigned short* kp = qkv + (base + p) * 768 + 256 + head * 64;
#pragma unroll
    for (int ks = 0; ks < 2; ks++) kf[ni][ks].u = *(const uint4*)(kp + ks * 32 + quad * 8);
  }

  // --- S = Q K^T ---
  f32x4 s[4][4];
#pragma unroll
  for (int mi = 0; mi < 4; mi++)
#pragma unroll
    for (int ni = 0; ni < 4; ni++) {
      f32x4 z = {0.f, 0.f, 0.f, 0.f};
      z = __builtin_amdgcn_mfma_f32_16x16x32_bf16(qf[mi][0].s, kf[ni][0].s, z, 0, 0, 0);
      z = __builtin_amdgcn_mfma_f32_16x16x32_bf16(qf[mi][1].s, kf[ni][1].s, z, 0, 0, 0);
      s[mi][ni] = z;
    }

  // --- softmax (row = mi*16+quad*4+r), cols masked >=49; 1/sum folded in ---
  bool valid[4];
#pragma unroll
  for (int ni = 0; ni < 4; ni++) valid[ni] = (ni * 16 + lid) < 49;
  const float SC = 0.18033688011112042f;  // (1/8) * log2(e)
#pragma unroll
  for (int mi = 0; mi < 4; mi++) {
#pragma unroll
    for (int r = 0; r < 4; r++) {
      float m = -3.0e38f;
#pragma unroll
      for (int ni = 0; ni < 4; ni++) m = valid[ni] ? fmaxf(m, s[mi][ni][r]) : m;
#pragma unroll
      for (int d = 1; d < 16; d <<= 1) m = fmaxf(m, __shfl_xor(m, d, 64));
      float e[4]; float sum = 0.f;
#pragma unroll
      for (int ni = 0; ni < 4; ni++) {
        float t = valid[ni] ? exp2f((s[mi][ni][r] - m) * SC) : 0.f;
        e[ni] = t; sum += t;
      }
#pragma unroll
      for (int d = 1; d < 16; d <<= 1) sum += __shfl_xor(sum, d, 64);
      float inv = __builtin_amdgcn_rcpf(sum);
      int row = mi * 16 + quad * 4 + r;
#pragma unroll
      for (int ni = 0; ni < 4; ni++) {
        int col = ni * 16 + lid;
        *(unsigned short*)(Pb + row * 128 + (((col >> 3) ^ (row & 7)) << 4) + (col & 7) * 2) =
            f2bf(e[ni] * inv);
      }
    }
  }
  __syncthreads();

  // --- O = P V ---
  V16 pf[4][2];
#pragma unroll
  for (int mi = 0; mi < 4; mi++) {
    int row = mi * 16 + lid;
#pragma unroll
    for (int ks = 0; ks < 2; ks++) {
      int gl = ks * 4 + quad;
      pf[mi][ks].u = *(const uint4*)(Pb + row * 128 + ((gl ^ (row & 7)) << 4));
    }
  }
  f32x4 o[4][4];
#pragma unroll
  for (int mi = 0; mi < 4; mi++)
#pragma unroll
    for (int ni = 0; ni < 4; ni++) {
      f32x4 z = {0.f, 0.f, 0.f, 0.f};
      z = __builtin_amdgcn_mfma_f32_16x16x32_bf16(pf[mi][0].s, vf[0][ni].s, z, 0, 0, 0);
      z = __builtin_amdgcn_mfma_f32_16x16x32_bf16(pf[mi][1].s, vf[1][ni].s, z, 0, 0, 0);
      o[mi][ni] = z;
    }

  // --- store pixel-major bf16: oS[(b*3136+p)*256 + ch] ---
#pragma unroll
  for (int mi = 0; mi < 4; mi++) {
#pragma unroll
    for (int r = 0; r < 4; r++) {
      int q = mi * 16 + quad * 4 + r;
      if (q < 49) {
        int p = pix(q);
        size_t ob = (base + p) * 256 + head * 64;
#pragma unroll
        for (int ni = 0; ni < 4; ni++)
          oS[ob + ni * 16 + lid] = f2bf(o[mi][ni][r]);
      }
    }
  }
}

// --------------------------- kernel 4: merge + transpose --------------------
// out[b][c][p] = fp32( oR[b][p][c] + oC[b][p][c] ), coalesced both sides.
__global__ __launch_bounds__(256) void k_merge(const unsigned short* __restrict__ oR,
                                               const unsigned short* __restrict__ oC,
                                               float* __restrict__ out) {
  __shared__ float lds[32 * 66];   // [ch 0..31][px 0..63], stride 66 (pad)
  const int t = threadIdx.x;
  const int p0 = blockIdx.x * 64, c0 = blockIdx.y * 32, b = blockIdx.z;

  const int pl = t >> 2, cg = t & 3;
  size_t gi = ((size_t)(b * 3136 + p0 + pl)) * 256 + c0 + cg * 8;
  uint4 r1 = *(const uint4*)(oR + gi);
  uint4 r2 = *(const uint4*)(oC + gi);
  const uint32_t* a1 = (const uint32_t*)&r1;
  const uint32_t* a2 = (const uint32_t*)&r2;
#pragma unroll
  for (int j = 0; j < 4; j++) {
    float lo = bf2f(a1[j] << 16)        + bf2f(a2[j] << 16);
    float hi = bf2f(a1[j] & 0xFFFF0000u) + bf2f(a2[j] & 0xFFFF0000u);
    lds[(cg * 8 + j * 2)     * 66 + pl] = lo;
    lds[(cg * 8 + j * 2 + 1) * 66 + pl] = hi;
  }
  __syncthreads();

  const int lanec = t >> 4, pxl = (t & 15) * 4;
#pragma unroll
  for (int it = 0; it < 2; it++) {
    int c = it * 16 + lanec;    // 0..31
    float4 v;
    v.x = lds[c * 66 + pxl];
    v.y = lds[c * 66 + pxl + 1];
    v.z = lds[c * 66 + pxl + 2];
    v.w = lds[c * 66 + pxl + 3];
    *(float4*)(out + ((size_t)(b * 256 + c0 + c)) * 3136 + p0 + pxl) = v;
  }
}

// ------------------------------- launcher -----------------------------------
extern "C" void kernel_launch(void* const* d_in, const int* in_sizes, int n_in,
                              void* d_out, int out_size, void* d_ws, size_t ws_size,
                              hipStream_t stream) {
  (void)in_sizes; (void)n_in; (void)out_size; (void)ws_size;
  const float* x    = (const float*)d_in[0];
  const float* qk_w = (const float*)d_in[1];
  const float* v_w  = (const float*)d_in[2];
  float* out = (float*)d_out;
  char* ws = (char*)d_ws;
  unsigned short* Wb  = (unsigned short*)ws;                    //     393,216 B
  unsigned short* xT  = (unsigned short*)(ws + 393216);         //  51,380,224 B (reused as oR)
  unsigned short* qkv = (unsigned short*)(ws + 51773440ull);    // 154,140,672 B
  unsigned short* oR  = xT;                                     // alias (xT dead after k_conv)
  unsigned short* oC  = (unsigned short*)(ws + 205914112ull);   //  51,380,224 B

  hipLaunchKernelGGL(k_wconv, dim3(768), dim3(256), 0, stream, qk_w, v_w, Wb);
  hipLaunchKernelGGL(k_xpose, dim3(49, 8, 32), dim3(256), 0, stream, x, xT);
  hipLaunchKernelGGL(k_conv, dim3(4800), dim3(256), 0, stream, Wb, xT, qkv);
  hipLaunchKernelGGL(k_attn, dim3(4096), dim3(256), 0, stream, qkv, oR, oC);
  hipLaunchKernelGGL(k_merge, dim3(49, 8, 32), dim3(256), 0, stream, oR, oC, out);
}

// Round 3
// 386.845 us; speedup vs baseline: 3.1515x; 1.0700x over previous
//
#include <hip/hip_runtime.h>
#include <stdint.h>

// ---------------------------------------------------------------------------
// EW_MHSA_Hybrid: x(32,256,56,56) --1x1conv--> qk(512ch), v(256ch,ReLU)
// then 7x7 window attention over remote (dilated) + close (contiguous)
// partitions, summed. Output fp32 (32,256,56,56).
//
// ws layout (needs ~258 MB):
//   [0, 393216)             Wb  : bf16 weights [768 rows][512 B], XOR-swizzled
//   [393216, 51773440)      xT  : bf16 x pixel-major [b*3136+p][256], swizzled
//                                 (DEAD after k_conv -> reused as oR)
//   [51773440, 205914112)   qkv : bf16 [b*3136+p][768] (q|k|v, v has ReLU)
//   [205914112, 257294336)  oC  : bf16 close-attn out, pixel-major
// ---------------------------------------------------------------------------

typedef float f32x4 __attribute__((ext_vector_type(4)));
typedef __attribute__((ext_vector_type(8))) short short8;

union V16 { uint4 u; short8 s; unsigned short h[8]; };

typedef const __attribute__((address_space(1))) uint32_t* gp_t;
typedef __attribute__((address_space(3))) uint32_t* lp_t;

__device__ __forceinline__ void async16(const void* g, void* l) {
  __builtin_amdgcn_global_load_lds((gp_t)g, (lp_t)l, 16, 0, 0);
}

__device__ __forceinline__ unsigned short f2bf(float f) {
  union { float f; uint32_t u; } a; a.f = f;
  uint32_t u = a.u;
  return (unsigned short)((u + 0x7FFFu + ((u >> 16) & 1u)) >> 16); // RNE
}

__device__ __forceinline__ float bf2f(uint32_t bits_hi16) {
  union { uint32_t u; float f; } a; a.u = bits_hi16; return a.f;
}

// ------------------- kernel 0: weight convert (swizzled) --------------------
// Wb row o (512 B): [kb 0..3][ (gg ^ (o&7)) * 16B ], gg = (ch/8)&7, kb = ch/64.
__global__ __launch_bounds__(256) void k_wconv(const float* __restrict__ qk_w,
                                               const float* __restrict__ v_w,
                                               unsigned short* __restrict__ Wb) {
  int i = blockIdx.x * 256 + threadIdx.x;   // 768*32 = 24576 threads, 16B each
  int o = i >> 5, gidx = i & 31;
  int c0 = gidx * 8;
  const float* src = (o < 512) ? (qk_w + o * 256 + c0) : (v_w + (o - 512) * 256 + c0);
  unsigned short vv[8];
#pragma unroll
  for (int j = 0; j < 8; j++) vv[j] = f2bf(src[j]);
  uint4 u;
  u.x = (uint32_t)vv[0] | ((uint32_t)vv[1] << 16);
  u.y = (uint32_t)vv[2] | ((uint32_t)vv[3] << 16);
  u.z = (uint32_t)vv[4] | ((uint32_t)vv[5] << 16);
  u.w = (uint32_t)vv[6] | ((uint32_t)vv[7] << 16);
  int kb = gidx >> 3, gg = gidx & 7;
  char* dst = (char*)Wb + (size_t)o * 512 + kb * 128 + ((gg ^ (o & 7)) << 4);
  *(uint4*)dst = u;
}

// --------------------- kernel 1: x -> bf16 NHWC (swizzled) ------------------
__global__ __launch_bounds__(256) void k_xpose(const float* __restrict__ x,
                                               unsigned short* __restrict__ xT) {
  const int t = threadIdx.x;
  const int p = blockIdx.x * 64 + (t >> 2);
  const int sub = t & 3;
  const int c0 = blockIdx.y * 32 + sub * 8;
  const int b = blockIdx.z;
  const float* xp = x + ((size_t)(b * 256 + c0)) * 3136 + p;
  unsigned short vv[8];
#pragma unroll
  for (int j = 0; j < 8; j++) vv[j] = f2bf(xp[(size_t)j * 3136]);
  uint4 u;
  u.x = (uint32_t)vv[0] | ((uint32_t)vv[1] << 16);
  u.y = (uint32_t)vv[2] | ((uint32_t)vv[3] << 16);
  u.z = (uint32_t)vv[4] | ((uint32_t)vv[5] << 16);
  u.w = (uint32_t)vv[6] | ((uint32_t)vv[7] << 16);
  const int g = (c0 >> 3) & 7;
  const int kb = c0 >> 6;
  char* dst = (char*)xT + ((size_t)(b * 3136 + p)) * 512 + kb * 128 + ((g ^ (p & 7)) << 4);
  *(uint4*)dst = u;
}

// ------------------------- kernel 2: conv GEMM (MFMA) -----------------------
// grid flat 4800 with XCD-batch affinity: batch b runs on XCD b%8.
// Both A (W) and B (x) staged via global_load_lds; frags via ds_read_b128.
__global__ __launch_bounds__(256) void k_conv(const unsigned short* __restrict__ Wb,
                                              const unsigned short* __restrict__ xT,
                                              unsigned short* __restrict__ qkv) {
  __shared__ uint4 lds4[2048];     // 32 KB: A-tile 16 KB | B-tile 16 KB
  char* ldsA = (char*)lds4;
  char* ldsB = (char*)lds4 + 16384;
  const int bi = blockIdx.x;                 // 0..4799
  const int xcd = bi & 7, g = bi >> 3;       // g: 0..599
  const int bgrp = g / 150;
  const int rem = g - bgrp * 150;
  const int b = xcd + 8 * bgrp;
  const int ot = rem / 25;
  const int pt = rem - ot * 25;
  const int p0 = pt * 128, o0 = ot * 128;
  const bool isv = (ot >= 4);

  const int tid = threadIdx.x;
  const int lane = tid & 63, wave = tid >> 6;
  const int lid = lane & 15, quad = lane >> 4;
  const int m_off = (wave & 1) * 64, n_off = (wave >> 1) * 64;
  const int psub = lane >> 3, chunk = lane & 7;
  const size_t rowb = (size_t)(b * 3136 + p0);
  const char* xTb = (const char*)xT;
  const char* Wbb = (const char*)Wb;

  f32x4 acc[4][4];
#pragma unroll
  for (int mi = 0; mi < 4; mi++)
#pragma unroll
    for (int ni = 0; ni < 4; ni++) { f32x4 z = {0.f, 0.f, 0.f, 0.f}; acc[mi][ni] = z; }

  for (int kk = 0; kk < 256; kk += 64) {
#pragma unroll
    for (int r = 0; r < 4; r++) {
      int i = wave * 4 + r;                          // 16 rounds cover 128 rows
      const char* ga = Wbb + (size_t)(o0 + i * 8 + psub) * 512 + kk * 2 + chunk * 16;
      async16(ga, ldsA + i * 1024);
      const char* gb = xTb + (rowb + i * 8 + psub) * 512 + kk * 2 + chunk * 16;
      async16(gb, ldsB + i * 1024);
    }
    __syncthreads();

    V16 a[4][2], bf[4][2];
#pragma unroll
    for (int mi = 0; mi < 4; mi++) {
      int ro = m_off + mi * 16 + lid;                // LDS A row 0..127
#pragma unroll
      for (int ks = 0; ks < 2; ks++) {
        int gl = ks * 4 + quad;
        a[mi][ks].u = *(const uint4*)(ldsA + ro * 128 + ((gl ^ (ro & 7)) << 4));
      }
    }
#pragma unroll
    for (int ni = 0; ni < 4; ni++) {
      int px = n_off + ni * 16 + lid;                // LDS B row 0..127
#pragma unroll
      for (int ks = 0; ks < 2; ks++) {
        int gl = ks * 4 + quad;
        bf[ni][ks].u = *(const uint4*)(ldsB + px * 128 + ((gl ^ (px & 7)) << 4));
      }
    }
#pragma unroll
    for (int mi = 0; mi < 4; mi++)
#pragma unroll
      for (int ni = 0; ni < 4; ni++) {
        acc[mi][ni] = __builtin_amdgcn_mfma_f32_16x16x32_bf16(a[mi][0].s, bf[ni][0].s, acc[mi][ni], 0, 0, 0);
        acc[mi][ni] = __builtin_amdgcn_mfma_f32_16x16x32_bf16(a[mi][1].s, bf[ni][1].s, acc[mi][ni], 0, 0, 0);
      }
    __syncthreads();
  }

#pragma unroll
  for (int mi = 0; mi < 4; mi++) {
    int o = o0 + m_off + mi * 16 + quad * 4;
#pragma unroll
    for (int ni = 0; ni < 4; ni++) {
      int px = p0 + n_off + ni * 16 + lid;
      if (px < 3136) {
        f32x4 v = acc[mi][ni];
        if (isv) {
          v.x = fmaxf(v.x, 0.f); v.y = fmaxf(v.y, 0.f);
          v.z = fmaxf(v.z, 0.f); v.w = fmaxf(v.w, 0.f);
        }
        ushort4 u;
        u.x = f2bf(v.x); u.y = f2bf(v.y); u.z = f2bf(v.z); u.w = f2bf(v.w);
        *(ushort4*)(qkv + ((size_t)(b * 3136 + px)) * 768 + o) = u;
      }
    }
  }
}

// --------------------------- kernel 3: attention ----------------------------
// Both partitions in one dispatch, XCD-batch affinity. One block per
// (partition, window, batch); wave = head. 49 px padded to 64.
// Output: pixel-major bf16 scratch (oR remote / oC close).
__global__ __launch_bounds__(256) void k_attn(const unsigned short* __restrict__ qkv,
                                              unsigned short* __restrict__ oR,
                                              unsigned short* __restrict__ oC) {
  __shared__ uint4 smem4[2048];   // 32 KB = 4 waves x 8 KB P-buffer
  const int bi = blockIdx.x;                  // 0..4095
  const int xcd = bi & 7, g = bi >> 3;        // g: 0..511
  const int b = ((g >> 7) << 3) + xcd;        // batch: b%8 == xcd
  const int rem = g & 127;
  const int part = rem >> 6;                  // 0=remote, 1=close
  const int w = rem & 63;
  const int i1 = w >> 3, i2 = w & 7;
  const int off = part ? (i1 * 392 + i2 * 7) : (i1 * 56 + i2);
  const int sh  = part ? 56 : 448;
  const int sw  = part ? 1 : 8;
  unsigned short* __restrict__ oS = part ? oC : oR;

  const int lane = threadIdx.x & 63;
  const int head = threadIdx.x >> 6;
  const int lid = lane & 15, quad = lane >> 4;
  char* Pb = (char*)smem4 + head * 8192;
  const size_t base = (size_t)b * 3136;

  auto pix = [&](int t) -> int {  // window slot t (0..48) -> pixel index
    int h1 = (t * 37) >> 8;       // t/7 for t<=48
    int w1 = t - h1 * 7;
    return off + h1 * sh + w1 * sw;
  };

  // --- V B-frags: B[k=key][n=dh] ---
  V16 vf[2][4];
#pragma unroll
  for (int ks = 0; ks < 2; ks++)
#pragma unroll
    for (int j = 0; j < 8; j++) {
      int key = ks * 32 + quad * 8 + j;
      int p = pix(min(key, 48));                       // P cols >=49 are 0
      const unsigned short* vp = qkv + (base + p) * 768 + 512 + head * 64;
#pragma unroll
      for (int ni = 0; ni < 4; ni++) vf[ks][ni].h[j] = vp[ni * 16 + lid];
    }

  // --- Q A-frags / K^T B-frags (16B per lane) ---
  V16 qf[4][2], kf[4][2];
#pragma unroll
  for (int mi = 0; mi < 4; mi++) {
    int p = pix(min(mi * 16 + lid, 48));
    const unsigned short* qp = qkv + (base + p) * 768 + head * 64;
#pragma unroll
    for (int ks = 0; ks < 2; ks++) qf[mi][ks].u = *(const uint4*)(qp + ks * 32 + quad * 8);
  }
#pragma unroll
  for (int ni = 0; ni < 4; ni++) {
    int p = pix(min(ni * 16 + lid, 48));
    const unsigned short* kp = qkv + (base + p) * 768 + 256 + head * 64;
#pragma unroll
    for (int ks = 0; ks < 2; ks++) kf[ni][ks].u = *(const uint4*)(kp + ks * 32 + quad * 8);
  }

  // --- S = Q K^T ---
  f32x4 s[4][4];
#pragma unroll
  for (int mi = 0; mi < 4; mi++)
#pragma unroll
    for (int ni = 0; ni < 4; ni++) {
      f32x4 z = {0.f, 0.f, 0.f, 0.f};
      z = __builtin_amdgcn_mfma_f32_16x16x32_bf16(qf[mi][0].s, kf[ni][0].s, z, 0, 0, 0);
      z = __builtin_amdgcn_mfma_f32_16x16x32_bf16(qf[mi][1].s, kf[ni][1].s, z, 0, 0, 0);
      s[mi][ni] = z;
    }

  // --- softmax (row = mi*16+quad*4+r), cols masked >=49; 1/sum folded in ---
  bool valid[4];
#pragma unroll
  for (int ni = 0; ni < 4; ni++) valid[ni] = (ni * 16 + lid) < 49;
  const float SC = 0.18033688011112042f;  // (1/8) * log2(e)
#pragma unroll
  for (int mi = 0; mi < 4; mi++) {
#pragma unroll
    for (int r = 0; r < 4; r++) {
      float m = -3.0e38f;
#pragma unroll
      for (int ni = 0; ni < 4; ni++) m = valid[ni] ? fmaxf(m, s[mi][ni][r]) : m;
#pragma unroll
      for (int d = 1; d < 16; d <<= 1) m = fmaxf(m, __shfl_xor(m, d, 64));
      float e[4]; float sum = 0.f;
#pragma unroll
      for (int ni = 0; ni < 4; ni++) {
        float t = valid[ni] ? exp2f((s[mi][ni][r] - m) * SC) : 0.f;
        e[ni] = t; sum += t;
      }
#pragma unroll
      for (int d = 1; d < 16; d <<= 1) sum += __shfl_xor(sum, d, 64);
      float inv = __builtin_amdgcn_rcpf(sum);
      int row = mi * 16 + quad * 4 + r;
#pragma unroll
      for (int ni = 0; ni < 4; ni++) {
        int col = ni * 16 + lid;
        *(unsigned short*)(Pb + row * 128 + (((col >> 3) ^ (row & 7)) << 4) + (col & 7) * 2) =
            f2bf(e[ni] * inv);
      }
    }
  }
  __syncthreads();

  // --- O = P V ---
  V16 pf[4][2];
#pragma unroll
  for (int mi = 0; mi < 4; mi++) {
    int row = mi * 16 + lid;
#pragma unroll
    for (int ks = 0; ks < 2; ks++) {
      int gl = ks * 4 + quad;
      pf[mi][ks].u = *(const uint4*)(Pb + row * 128 + ((gl ^ (row & 7)) << 4));
    }
  }
  f32x4 o[4][4];
#pragma unroll
  for (int mi = 0; mi < 4; mi++)
#pragma unroll
    for (int ni = 0; ni < 4; ni++) {
      f32x4 z = {0.f, 0.f, 0.f, 0.f};
      z = __builtin_amdgcn_mfma_f32_16x16x32_bf16(pf[mi][0].s, vf[0][ni].s, z, 0, 0, 0);
      z = __builtin_amdgcn_mfma_f32_16x16x32_bf16(pf[mi][1].s, vf[1][ni].s, z, 0, 0, 0);
      o[mi][ni] = z;
    }

  // --- store pixel-major bf16: oS[(b*3136+p)*256 + ch] ---
#pragma unroll
  for (int mi = 0; mi < 4; mi++) {
#pragma unroll
    for (int r = 0; r < 4; r++) {
      int q = mi * 16 + quad * 4 + r;
      if (q < 49) {
        int p = pix(q);
        size_t ob = (base + p) * 256 + head * 64;
#pragma unroll
        for (int ni = 0; ni < 4; ni++)
          oS[ob + ni * 16 + lid] = f2bf(o[mi][ni][r]);
      }
    }
  }
}

// --------------------------- kernel 4: merge + transpose --------------------
// out[b][c][p] = fp32( oR[b][p][c] + oC[b][p][c] ), coalesced both sides.
__global__ __launch_bounds__(256) void k_merge(const unsigned short* __restrict__ oR,
                                               const unsigned short* __restrict__ oC,
                                               float* __restrict__ out) {
  __shared__ float lds[32 * 66];   // [ch 0..31][px 0..63], stride 66 (pad)
  const int t = threadIdx.x;
  const int p0 = blockIdx.x * 64, c0 = blockIdx.y * 32, b = blockIdx.z;

  const int pl = t >> 2, cg = t & 3;
  size_t gi = ((size_t)(b * 3136 + p0 + pl)) * 256 + c0 + cg * 8;
  uint4 r1 = *(const uint4*)(oR + gi);
  uint4 r2 = *(const uint4*)(oC + gi);
  const uint32_t* a1 = (const uint32_t*)&r1;
  const uint32_t* a2 = (const uint32_t*)&r2;
#pragma unroll
  for (int j = 0; j < 4; j++) {
    float lo = bf2f(a1[j] << 16)        + bf2f(a2[j] << 16);
    float hi = bf2f(a1[j] & 0xFFFF0000u) + bf2f(a2[j] & 0xFFFF0000u);
    lds[(cg * 8 + j * 2)     * 66 + pl] = lo;
    lds[(cg * 8 + j * 2 + 1) * 66 + pl] = hi;
  }
  __syncthreads();

  const int lanec = t >> 4, pxl = (t & 15) * 4;
#pragma unroll
  for (int it = 0; it < 2; it++) {
    int c = it * 16 + lanec;    // 0..31
    float4 v;
    v.x = lds[c * 66 + pxl];
    v.y = lds[c * 66 + pxl + 1];
    v.z = lds[c * 66 + pxl + 2];
    v.w = lds[c * 66 + pxl + 3];
    *(float4*)(out + ((size_t)(b * 256 + c0 + c)) * 3136 + p0 + pxl) = v;
  }
}

// ------------------------------- launcher -----------------------------------
extern "C" void kernel_launch(void* const* d_in, const int* in_sizes, int n_in,
                              void* d_out, int out_size, void* d_ws, size_t ws_size,
                              hipStream_t stream) {
  (void)in_sizes; (void)n_in; (void)out_size; (void)ws_size;
  const float* x    = (const float*)d_in[0];
  const float* qk_w = (const float*)d_in[1];
  const float* v_w  = (const float*)d_in[2];
  float* out = (float*)d_out;
  char* ws = (char*)d_ws;
  unsigned short* Wb  = (unsigned short*)ws;                    //     393,216 B
  unsigned short* xT  = (unsigned short*)(ws + 393216);         //  51,380,224 B (reused as oR)
  unsigned short* qkv = (unsigned short*)(ws + 51773440ull);    // 154,140,672 B
  unsigned short* oR  = xT;                                     // alias (xT dead after k_conv)
  unsigned short* oC  = (unsigned short*)(ws + 205914112ull);   //  51,380,224 B

  hipLaunchKernelGGL(k_wconv, dim3(96), dim3(256), 0, stream, qk_w, v_w, Wb);
  hipLaunchKernelGGL(k_xpose, dim3(49, 8, 32), dim3(256), 0, stream, x, xT);
  hipLaunchKernelGGL(k_conv, dim3(4800), dim3(256), 0, stream, Wb, xT, qkv);
  hipLaunchKernelGGL(k_attn, dim3(4096), dim3(256), 0, stream, qkv, oR, oC);
  hipLaunchKernelGGL(k_merge, dim3(49, 8, 32), dim3(256), 0, stream, oR, oC, out);
}

// Round 4
// 380.391 us; speedup vs baseline: 3.2050x; 1.0170x over previous
//
#include <hip/hip_runtime.h>
#include <stdint.h>

// ---------------------------------------------------------------------------
// EW_MHSA_Hybrid: x(32,256,56,56) --1x1conv--> qk(512ch), v(256ch,ReLU)
// then 7x7 window attention over remote (dilated) + close (contiguous)
// partitions, summed. Output fp32 (32,256,56,56).
//
// ws layout (needs ~258 MB):
//   [0, 393216)             Wb  : bf16 weights [768 rows][512 B], XOR-swizzled
//   [393216, 51773440)      xT  : bf16 x pixel-major [b*3136+p][256], swizzled
//                                 (DEAD after k_conv -> reused as oR)
//   [51773440, 205914112)   qkv : bf16 [b*3136+p][768] (q|k|v; q pre-scaled by
//                                 SCALE*log2e; v has ReLU)
//   [205914112, 257294336)  oC  : bf16 close-attn out, pixel-major
// ---------------------------------------------------------------------------

typedef float f32x4 __attribute__((ext_vector_type(4)));
typedef __attribute__((ext_vector_type(8))) short short8;

union V16 { uint4 u; short8 s; unsigned short h[8]; };

typedef const __attribute__((address_space(1))) uint32_t* gp_t;
typedef __attribute__((address_space(3))) uint32_t* lp_t;

__device__ __forceinline__ void async16(const void* g, void* l) {
  __builtin_amdgcn_global_load_lds((gp_t)g, (lp_t)l, 16, 0, 0);
}

__device__ __forceinline__ unsigned short f2bf(float f) {      // RNE
  union { float f; uint32_t u; } a; a.f = f;
  uint32_t u = a.u;
  return (unsigned short)((u + 0x7FFFu + ((u >> 16) & 1u)) >> 16);
}

__device__ __forceinline__ unsigned short f2bf_rhu(float f) {  // round-half-up
  union { float f; uint32_t u; } a; a.f = f;
  return (unsigned short)((a.u + 0x8000u) >> 16);
}

__device__ __forceinline__ float bf2f(uint32_t bits_hi16) {
  union { uint32_t u; float f; } a; a.u = bits_hi16; return a.f;
}

// ------------------- kernel 0: weight convert (swizzled) --------------------
__global__ __launch_bounds__(256) void k_wconv(const float* __restrict__ qk_w,
                                               const float* __restrict__ v_w,
                                               unsigned short* __restrict__ Wb) {
  int i = blockIdx.x * 256 + threadIdx.x;   // 768*32 = 24576 threads, 16B each
  int o = i >> 5, gidx = i & 31;
  int c0 = gidx * 8;
  const float* src = (o < 512) ? (qk_w + o * 256 + c0) : (v_w + (o - 512) * 256 + c0);
  unsigned short vv[8];
#pragma unroll
  for (int j = 0; j < 8; j++) vv[j] = f2bf(src[j]);
  uint4 u;
  u.x = (uint32_t)vv[0] | ((uint32_t)vv[1] << 16);
  u.y = (uint32_t)vv[2] | ((uint32_t)vv[3] << 16);
  u.z = (uint32_t)vv[4] | ((uint32_t)vv[5] << 16);
  u.w = (uint32_t)vv[6] | ((uint32_t)vv[7] << 16);
  int kb = gidx >> 3, gg = gidx & 7;
  char* dst = (char*)Wb + (size_t)o * 512 + kb * 128 + ((gg ^ (o & 7)) << 4);
  *(uint4*)dst = u;
}

// --------------------- kernel 1: x -> bf16 NHWC (swizzled) ------------------
__global__ __launch_bounds__(256) void k_xpose(const float* __restrict__ x,
                                               unsigned short* __restrict__ xT) {
  const int t = threadIdx.x;
  const int p = blockIdx.x * 64 + (t >> 2);
  const int sub = t & 3;
  const int c0 = blockIdx.y * 32 + sub * 8;
  const int b = blockIdx.z;
  const float* xp = x + ((size_t)(b * 256 + c0)) * 3136 + p;
  unsigned short vv[8];
#pragma unroll
  for (int j = 0; j < 8; j++) vv[j] = f2bf(xp[(size_t)j * 3136]);
  uint4 u;
  u.x = (uint32_t)vv[0] | ((uint32_t)vv[1] << 16);
  u.y = (uint32_t)vv[2] | ((uint32_t)vv[3] << 16);
  u.z = (uint32_t)vv[4] | ((uint32_t)vv[5] << 16);
  u.w = (uint32_t)vv[6] | ((uint32_t)vv[7] << 16);
  const int g = (c0 >> 3) & 7;
  const int kb = c0 >> 6;
  char* dst = (char*)xT + ((size_t)(b * 3136 + p)) * 512 + kb * 128 + ((g ^ (p & 7)) << 4);
  *(uint4*)dst = u;
}

// ------------------------- kernel 2: conv GEMM (MFMA) -----------------------
// grid flat 4800 with XCD-batch affinity. A (W) and B (x) via global_load_lds.
// q channels (ot<2) pre-scaled by SCALE*log2e so attention exp is raw exp2.
__global__ __launch_bounds__(256) void k_conv(const unsigned short* __restrict__ Wb,
                                              const unsigned short* __restrict__ xT,
                                              unsigned short* __restrict__ qkv) {
  __shared__ uint4 lds4[2048];     // 32 KB: A-tile 16 KB | B-tile 16 KB
  char* ldsA = (char*)lds4;
  char* ldsB = (char*)lds4 + 16384;
  const int bi = blockIdx.x;                 // 0..4799
  const int xcd = bi & 7, g = bi >> 3;       // g: 0..599
  const int bgrp = g / 150;
  const int rem = g - bgrp * 150;
  const int b = xcd + 8 * bgrp;
  const int ot = rem / 25;
  const int pt = rem - ot * 25;
  const int p0 = pt * 128, o0 = ot * 128;
  const bool isv = (ot >= 4);
  const float qs = (ot < 2) ? 0.18033688011112042f : 1.0f;  // SCALE*log2(e)

  const int tid = threadIdx.x;
  const int lane = tid & 63, wave = tid >> 6;
  const int lid = lane & 15, quad = lane >> 4;
  const int m_off = (wave & 1) * 64, n_off = (wave >> 1) * 64;
  const int psub = lane >> 3, chunk = lane & 7;
  const size_t rowb = (size_t)(b * 3136 + p0);
  const char* xTb = (const char*)xT;
  const char* Wbb = (const char*)Wb;

  f32x4 acc[4][4];
#pragma unroll
  for (int mi = 0; mi < 4; mi++)
#pragma unroll
    for (int ni = 0; ni < 4; ni++) { f32x4 z = {0.f, 0.f, 0.f, 0.f}; acc[mi][ni] = z; }

  for (int kk = 0; kk < 256; kk += 64) {
#pragma unroll
    for (int r = 0; r < 4; r++) {
      int i = wave * 4 + r;
      const char* ga = Wbb + (size_t)(o0 + i * 8 + psub) * 512 + kk * 2 + chunk * 16;
      async16(ga, ldsA + i * 1024);
      const char* gb = xTb + (rowb + i * 8 + psub) * 512 + kk * 2 + chunk * 16;
      async16(gb, ldsB + i * 1024);
    }
    __syncthreads();

    V16 a[4][2], bf[4][2];
#pragma unroll
    for (int mi = 0; mi < 4; mi++) {
      int ro = m_off + mi * 16 + lid;
#pragma unroll
      for (int ks = 0; ks < 2; ks++) {
        int gl = ks * 4 + quad;
        a[mi][ks].u = *(const uint4*)(ldsA + ro * 128 + ((gl ^ (ro & 7)) << 4));
      }
    }
#pragma unroll
    for (int ni = 0; ni < 4; ni++) {
      int px = n_off + ni * 16 + lid;
#pragma unroll
      for (int ks = 0; ks < 2; ks++) {
        int gl = ks * 4 + quad;
        bf[ni][ks].u = *(const uint4*)(ldsB + px * 128 + ((gl ^ (px & 7)) << 4));
      }
    }
#pragma unroll
    for (int mi = 0; mi < 4; mi++)
#pragma unroll
      for (int ni = 0; ni < 4; ni++) {
        acc[mi][ni] = __builtin_amdgcn_mfma_f32_16x16x32_bf16(a[mi][0].s, bf[ni][0].s, acc[mi][ni], 0, 0, 0);
        acc[mi][ni] = __builtin_amdgcn_mfma_f32_16x16x32_bf16(a[mi][1].s, bf[ni][1].s, acc[mi][ni], 0, 0, 0);
      }
    __syncthreads();
  }

#pragma unroll
  for (int mi = 0; mi < 4; mi++) {
    int o = o0 + m_off + mi * 16 + quad * 4;
#pragma unroll
    for (int ni = 0; ni < 4; ni++) {
      int px = p0 + n_off + ni * 16 + lid;
      if (px < 3136) {
        f32x4 v = acc[mi][ni];
        v.x *= qs; v.y *= qs; v.z *= qs; v.w *= qs;
        if (isv) {
          v.x = fmaxf(v.x, 0.f); v.y = fmaxf(v.y, 0.f);
          v.z = fmaxf(v.z, 0.f); v.w = fmaxf(v.w, 0.f);
        }
        ushort4 u;
        u.x = f2bf(v.x); u.y = f2bf(v.y); u.z = f2bf(v.z); u.w = f2bf(v.w);
        *(ushort4*)(qkv + ((size_t)(b * 3136 + px)) * 768 + o) = u;
      }
    }
  }
}

// --------------------------- kernel 3: attention ----------------------------
// One block per (partition, window, batch), XCD-batch affinity; wave = head.
// S = QK^T (MFMA, C-layout rows=q cols=key). exp2 (no max shift; logits tiny).
// Unnormalized bf16 P -> LDS row-major [q][key]. Then O^T = V^T * P^T:
//   A = V^T (64 scalar loads), B = P^T (= row-major P, b128 reads),
//   rowsum via ones-A MFMA; normalize at the 8-B packed epilogue stores.
__global__ __launch_bounds__(256) void k_attn(const unsigned short* __restrict__ qkv,
                                              unsigned short* __restrict__ oR,
                                              unsigned short* __restrict__ oC) {
  __shared__ uint4 smem4[2048];   // 32 KB = 4 waves x 8 KB P-buffer
  const int bi = blockIdx.x;                  // 0..4095
  const int xcd = bi & 7, g = bi >> 3;        // g: 0..511
  const int b = ((g >> 7) << 3) + xcd;        // batch: b%8 == xcd
  const int rem = g & 127;
  const int part = rem >> 6;                  // 0=remote, 1=close
  const int w = rem & 63;
  const int i1 = w >> 3, i2 = w & 7;
  const int off = part ? (i1 * 392 + i2 * 7) : (i1 * 56 + i2);
  const int sh  = part ? 56 : 448;
  const int sw  = part ? 1 : 8;

  const int lane = threadIdx.x & 63;
  const int head = threadIdx.x >> 6;
  const int lid = lane & 15, quad = lane >> 4;
  char* Pb = (char*)smem4 + head * 8192;
  const unsigned short* __restrict__ qkvb = qkv + (size_t)b * 3136 * 768;
  unsigned short* __restrict__ oSb = (part ? oC : oR) + (size_t)b * 3136 * 256;

  auto pix = [&](int t) -> int {  // window slot t (0..48) -> pixel index
    int h1 = (t * 37) >> 8;       // t/7 for t<=48
    int w1 = t - h1 * 7;
    return off + h1 * sh + w1 * sw;
  };

  // --- V^T A-frags: A[m=ch][k=key]; lane m=lid -> ch = mi*16+lid ---
  V16 va[4][2];
#pragma unroll
  for (int ks = 0; ks < 2; ks++)
#pragma unroll
    for (int j = 0; j < 8; j++) {
      int key = ks * 32 + quad * 8 + j;
      int p = pix(min(key, 48));               // clamp; P cols >=49 are 0
      const unsigned short* vp = qkvb + p * 768 + 512 + head * 64 + lid;
#pragma unroll
      for (int mi = 0; mi < 4; mi++) va[mi][ks].h[j] = vp[mi * 16];
    }

  // --- Q A-frags / K^T B-frags (16B per lane) ---
  V16 qf[4][2], kf[4][2];
#pragma unroll
  for (int mi = 0; mi < 4; mi++) {
    int p = pix(min(mi * 16 + lid, 48));
    const unsigned short* qp = qkvb + p * 768 + head * 64;
#pragma unroll
    for (int ks = 0; ks < 2; ks++) qf[mi][ks].u = *(const uint4*)(qp + ks * 32 + quad * 8);
  }
#pragma unroll
  for (int ni = 0; ni < 4; ni++) {
    int p = pix(min(ni * 16 + lid, 48));
    const unsigned short* kp = qkvb + p * 768 + 256 + head * 64;
#pragma unroll
    for (int ks = 0; ks < 2; ks++) kf[ni][ks].u = *(const uint4*)(kp + ks * 32 + quad * 8);
  }

  // --- S = QK^T (q pre-scaled by SCALE*log2e in k_conv) ---
  f32x4 s[4][4];
#pragma unroll
  for (int mi = 0; mi < 4; mi++)
#pragma unroll
    for (int ni = 0; ni < 4; ni++) {
      f32x4 z = {0.f, 0.f, 0.f, 0.f};
      z = __builtin_amdgcn_mfma_f32_16x16x32_bf16(qf[mi][0].s, kf[ni][0].s, z, 0, 0, 0);
      z = __builtin_amdgcn_mfma_f32_16x16x32_bf16(qf[mi][1].s, kf[ni][1].s, z, 0, 0, 0);
      s[mi][ni] = z;
    }

  // --- unnormalized P = exp2(S), masked cols, to LDS row-major [q][key] ---
  bool kvalid[4];
#pragma unroll
  for (int ni = 0; ni < 4; ni++) kvalid[ni] = (ni * 16 + lid) < 49;
  const int cl2 = (lid & 7) * 2;
#pragma unroll
  for (int mi = 0; mi < 4; mi++) {
#pragma unroll
    for (int r = 0; r < 4; r++) {
      int row = mi * 16 + quad * 4 + r;
      char* rp = Pb + row * 128;
      int rx = row & 7;
#pragma unroll
      for (int ni = 0; ni < 4; ni++) {
        float t = kvalid[ni] ? __builtin_amdgcn_exp2f(s[mi][ni][r]) : 0.f;
        int colgrp = ni * 2 + (lid >> 3);
        *(unsigned short*)(rp + (((colgrp ^ rx) << 4) + cl2)) = f2bf_rhu(t);
      }
    }
  }
  __syncthreads();   // each wave reads only its own P; barrier for DS ordering

  // --- P^T B-frags: B[k=key][n=q]; lane n=lid -> q = ni*16+lid ---
  V16 pt[4][2];
#pragma unroll
  for (int ni = 0; ni < 4; ni++) {
    int row = ni * 16 + lid;                   // q row of P
#pragma unroll
    for (int ks = 0; ks < 2; ks++) {
      int gl = ks * 4 + quad;
      pt[ni][ks].u = *(const uint4*)(Pb + row * 128 + ((gl ^ (row & 7)) << 4));
    }
  }

  // --- rowsum(q) via ones-A MFMA: D[.][q] = sum_k P^T[k][q] ---
  V16 ones;
#pragma unroll
  for (int j = 0; j < 8; j++) ones.h[j] = 0x3F80;   // bf16 1.0
  float inv[4];
  int pq[4]; bool qv[4];
#pragma unroll
  for (int ni = 0; ni < 4; ni++) {
    f32x4 z = {0.f, 0.f, 0.f, 0.f};
    z = __builtin_amdgcn_mfma_f32_16x16x32_bf16(ones.s, pt[ni][0].s, z, 0, 0, 0);
    z = __builtin_amdgcn_mfma_f32_16x16x32_bf16(ones.s, pt[ni][1].s, z, 0, 0, 0);
    inv[ni] = __builtin_amdgcn_rcpf(z[0]);
    int q = ni * 16 + lid;
    qv[ni] = q < 49;
    pq[ni] = pix(qv[ni] ? q : 48);
  }

  // --- O^T = V^T P^T; C-layout: row=ch (4 consecutive per lane), col=q ---
#pragma unroll
  for (int mi = 0; mi < 4; mi++) {
    f32x4 om[4];
#pragma unroll
    for (int ni = 0; ni < 4; ni++) {
      f32x4 z = {0.f, 0.f, 0.f, 0.f};
      z = __builtin_amdgcn_mfma_f32_16x16x32_bf16(va[mi][0].s, pt[ni][0].s, z, 0, 0, 0);
      z = __builtin_amdgcn_mfma_f32_16x16x32_bf16(va[mi][1].s, pt[ni][1].s, z, 0, 0, 0);
      om[ni] = z;
    }
#pragma unroll
    for (int ni = 0; ni < 4; ni++) {
      if (qv[ni]) {
        float iv = inv[ni];
        uint32_t lo = ((uint32_t)f2bf_rhu(om[ni][0] * iv)) | ((uint32_t)f2bf_rhu(om[ni][1] * iv) << 16);
        uint32_t hi = ((uint32_t)f2bf_rhu(om[ni][2] * iv)) | ((uint32_t)f2bf_rhu(om[ni][3] * iv) << 16);
        uint2 st; st.x = lo; st.y = hi;
        *(uint2*)(oSb + pq[ni] * 256 + head * 64 + mi * 16 + quad * 4) = st;
      }
    }
  }
}

// --------------------------- kernel 4: merge + transpose --------------------
// out[b][c][p] = fp32( oR[b][p][c] + oC[b][p][c] ), coalesced both sides.
__global__ __launch_bounds__(256) void k_merge(const unsigned short* __restrict__ oR,
                                               const unsigned short* __restrict__ oC,
                                               float* __restrict__ out) {
  __shared__ float lds[32 * 66];   // [ch 0..31][px 0..63], stride 66 (pad)
  const int t = threadIdx.x;
  const int p0 = blockIdx.x * 64, c0 = blockIdx.y * 32, b = blockIdx.z;

  const int pl = t >> 2, cg = t & 3;
  size_t gi = ((size_t)(b * 3136 + p0 + pl)) * 256 + c0 + cg * 8;
  uint4 r1 = *(const uint4*)(oR + gi);
  uint4 r2 = *(const uint4*)(oC + gi);
  const uint32_t* a1 = (const uint32_t*)&r1;
  const uint32_t* a2 = (const uint32_t*)&r2;
#pragma unroll
  for (int j = 0; j < 4; j++) {
    float lo = bf2f(a1[j] << 16)         + bf2f(a2[j] << 16);
    float hi = bf2f(a1[j] & 0xFFFF0000u) + bf2f(a2[j] & 0xFFFF0000u);
    lds[(cg * 8 + j * 2)     * 66 + pl] = lo;
    lds[(cg * 8 + j * 2 + 1) * 66 + pl] = hi;
  }
  __syncthreads();

  const int lanec = t >> 4, pxl = (t & 15) * 4;
#pragma unroll
  for (int it = 0; it < 2; it++) {
    int c = it * 16 + lanec;    // 0..31
    float4 v;
    v.x = lds[c * 66 + pxl];
    v.y = lds[c * 66 + pxl + 1];
    v.z = lds[c * 66 + pxl + 2];
    v.w = lds[c * 66 + pxl + 3];
    *(float4*)(out + ((size_t)(b * 256 + c0 + c)) * 3136 + p0 + pxl) = v;
  }
}

// ------------------------------- launcher -----------------------------------
extern "C" void kernel_launch(void* const* d_in, const int* in_sizes, int n_in,
                              void* d_out, int out_size, void* d_ws, size_t ws_size,
                              hipStream_t stream) {
  (void)in_sizes; (void)n_in; (void)out_size; (void)ws_size;
  const float* x    = (const float*)d_in[0];
  const float* qk_w = (const float*)d_in[1];
  const float* v_w  = (const float*)d_in[2];
  float* out = (float*)d_out;
  char* ws = (char*)d_ws;
  unsigned short* Wb  = (unsigned short*)ws;                    //     393,216 B
  unsigned short* xT  = (unsigned short*)(ws + 393216);         //  51,380,224 B (reused as oR)
  unsigned short* qkv = (unsigned short*)(ws + 51773440ull);    // 154,140,672 B
  unsigned short* oR  = xT;                                     // alias (xT dead after k_conv)
  unsigned short* oC  = (unsigned short*)(ws + 205914112ull);   //  51,380,224 B

  hipLaunchKernelGGL(k_wconv, dim3(96), dim3(256), 0, stream, qk_w, v_w, Wb);
  hipLaunchKernelGGL(k_xpose, dim3(49, 8, 32), dim3(256), 0, stream, x, xT);
  hipLaunchKernelGGL(k_conv, dim3(4800), dim3(256), 0, stream, Wb, xT, qkv);
  hipLaunchKernelGGL(k_attn, dim3(4096), dim3(256), 0, stream, qkv, oR, oC);
  hipLaunchKernelGGL(k_merge, dim3(49, 8, 32), dim3(256), 0, stream, oR, oC, out);
}